// Round 1
// baseline (1175.115 us; speedup 1.0000x reference)
//
#include <hip/hip_runtime.h>
#include <hip/hip_bf16.h>

// ---------------------------------------------------------------------------
// MLDecoder classification head, MI355X bf16-MFMA implementation.
// B=64, C_IN=2048, H=W=14 (S=196), D=768, FF=2048, G=100, NC=9605, NH=8, HD=96
// ---------------------------------------------------------------------------

#define B_    64
#define CIN_  2048
#define S_    196
#define D_    768
#define FF_   2048
#define G_    100
#define NC_   9605
#define NH_   8
#define HD_   96
#define DF_   97
#define BS_   (B_ * S_)   // 12544
#define BG_   (B_ * G_)   // 6400

typedef __bf16 bf16x8 __attribute__((ext_vector_type(8)));
typedef float  f32x4  __attribute__((ext_vector_type(4)));

__device__ __forceinline__ float bf2f(ushort u) {
  union { unsigned int i; float f; } v; v.i = ((unsigned int)u) << 16; return v.f;
}
__device__ __forceinline__ ushort f2bf(float f) {
  __hip_bfloat16 h = __float2bfloat16(f);
  return *reinterpret_cast<ushort*>(&h);
}

// ---------------- fp32 -> bf16 bulk convert (n divisible by 4) -------------
__global__ void k_cvt4(const float* __restrict__ in, ushort* __restrict__ out, int n4) {
  int i = blockIdx.x * blockDim.x + threadIdx.x;
  int stride = gridDim.x * blockDim.x;
  for (; i < n4; i += stride) {
    float4 v = ((const float4*)in)[i];
    ushort4 o;
    o.x = f2bf(v.x); o.y = f2bf(v.y); o.z = f2bf(v.z); o.w = f2bf(v.w);
    ((ushort4*)out)[i] = o;
  }
}

// ---------------- x [B][C][S] fp32 -> A_emb [B*S][C] bf16 ------------------
// grid (CIN/32, ceil(S/32)=7, B), block 256
__global__ __launch_bounds__(256) void k_xpose(const float* __restrict__ x, ushort* __restrict__ A) {
  __shared__ float tile[32][33];
  const int c0 = blockIdx.x * 32, s0 = blockIdx.y * 32, b = blockIdx.z;
  const int tx = threadIdx.x & 31, ty = threadIdx.x >> 5;   // ty in 0..7
  const float* xb = x + (size_t)b * CIN_ * S_;
  #pragma unroll
  for (int r = 0; r < 32; r += 8) {
    int c = c0 + ty + r, s = s0 + tx;
    tile[ty + r][tx] = (s < S_) ? xb[(size_t)c * S_ + s] : 0.f;
  }
  __syncthreads();
  #pragma unroll
  for (int r = 0; r < 32; r += 8) {
    int s = s0 + ty + r, c = c0 + tx;
    if (s < S_) A[((size_t)(b * S_ + s)) * CIN_ + c] = f2bf(tile[tx][ty + r]);
  }
}

// ---------------- tgt = LN(2*query_embed)*g1 + be1  [G,768] fp32 -----------
__global__ __launch_bounds__(256) void k_tgt(const float* __restrict__ qe,
    const float* __restrict__ g1, const float* __restrict__ be1, float* __restrict__ tgt) {
  const int g = blockIdx.x, t = threadIdx.x;
  __shared__ float r1[256], r2[256];
  float y[3]; float s = 0.f, sq = 0.f;
  const float* row = qe + (size_t)g * D_;
  #pragma unroll
  for (int i = 0; i < 3; ++i) { float v = 2.f * row[t + i * 256]; y[i] = v; s += v; sq += v * v; }
  r1[t] = s; r2[t] = sq; __syncthreads();
  for (int o = 128; o > 0; o >>= 1) { if (t < o) { r1[t] += r1[t + o]; r2[t] += r2[t + o]; } __syncthreads(); }
  const float mean = r1[0] * (1.f / D_);
  const float var  = r2[0] * (1.f / D_) - mean * mean;
  const float w = rsqrtf(var + 1e-5f);
  #pragma unroll
  for (int i = 0; i < 3; ++i) { int d = t + i * 256; tgt[(size_t)g * D_ + d] = (y[i] - mean) * w * g1[d] + be1[d]; }
}

// ---------------- q = tgt @ wq^T + bq   [G,768] fp32 -----------------------
__global__ __launch_bounds__(256) void k_qproj(const float* __restrict__ tgt,
    const float* __restrict__ wq, const float* __restrict__ bq, float* __restrict__ q) {
  const int g = blockIdx.x, t = threadIdx.x;
  __shared__ float ts[D_];
  for (int d = t; d < D_; d += 256) ts[d] = tgt[(size_t)g * D_ + d];
  __syncthreads();
  for (int e = t; e < D_; e += 256) {
    const float* w = wq + (size_t)e * D_;
    float acc = bq[e];
    for (int d = 0; d < D_; d += 4) {
      float4 wv = *(const float4*)&w[d];
      acc += ts[d] * wv.x + ts[d + 1] * wv.y + ts[d + 2] * wv.z + ts[d + 3] * wv.w;
    }
    q[(size_t)g * D_ + e] = acc;
  }
}

// ---------------- bf16 MFMA GEMM: C[M,N] = A[M,K] * B[N,K]^T + bias --------
// 128x128 tile, BK=32, 256 threads (4 waves, each 64x64 = 4x4 of 16x16x32)
__global__ __launch_bounds__(256) void k_gemm(const ushort* __restrict__ A, const ushort* __restrict__ B,
    const float* __restrict__ bias, float* __restrict__ Cf, ushort* __restrict__ Cb,
    int M, int N, int K, int relu) {
  __shared__ ushort As[128 * 32];
  __shared__ ushort Bs[128 * 32];
  const int t = threadIdx.x;
  const int m0 = blockIdx.y * 128, n0 = blockIdx.x * 128;
  const int lane = t & 63, wave = t >> 6;
  const int quad = lane >> 4, lrow = lane & 15;
  const int wr = (wave >> 1) * 64, wc = (wave & 1) * 64;
  const int srow = t >> 2, scol = (t & 3) * 8;
  f32x4 acc[4][4] = {};
  for (int k0 = 0; k0 < K; k0 += 32) {
    const ushort* ag = A + (size_t)(m0 + srow) * K + k0 + scol;
    const ushort* bg = B + (size_t)(n0 + srow) * K + k0 + scol;
    *(uint4*)&As[srow * 32 + scol]        = *(const uint4*)ag;
    *(uint4*)&As[(srow + 64) * 32 + scol] = *(const uint4*)(ag + (size_t)64 * K);
    *(uint4*)&Bs[srow * 32 + scol]        = *(const uint4*)bg;
    *(uint4*)&Bs[(srow + 64) * 32 + scol] = *(const uint4*)(bg + (size_t)64 * K);
    __syncthreads();
    bf16x8 af[4], bfr[4];
    #pragma unroll
    for (int i = 0; i < 4; ++i) af[i] = *(const bf16x8*)&As[(wr + i * 16 + lrow) * 32 + quad * 8];
    #pragma unroll
    for (int j = 0; j < 4; ++j) bfr[j] = *(const bf16x8*)&Bs[(wc + j * 16 + lrow) * 32 + quad * 8];
    #pragma unroll
    for (int i = 0; i < 4; ++i)
      #pragma unroll
      for (int j = 0; j < 4; ++j)
        acc[i][j] = __builtin_amdgcn_mfma_f32_16x16x32_bf16(af[i], bfr[j], acc[i][j], 0, 0, 0);
    __syncthreads();
  }
  #pragma unroll
  for (int i = 0; i < 4; ++i) {
    #pragma unroll
    for (int j = 0; j < 4; ++j) {
      const int gcol = n0 + wc + j * 16 + lrow;
      const float bv = bias ? bias[gcol] : 0.f;
      #pragma unroll
      for (int r = 0; r < 4; ++r) {
        const int grow = m0 + wr + i * 16 + quad * 4 + r;
        float v = acc[i][j][r] + bv;
        if (relu) v = fmaxf(v, 0.f);
        if (Cf) Cf[(size_t)grow * N + gcol] = v;
        else    Cb[(size_t)grow * N + gcol] = f2bf(v);
      }
    }
  }
}

// ---------------- attention: scores + softmax -> attn bf16 -----------------
// grid (NH, B), block 256. g processed in 5 chunks of 20.
__global__ __launch_bounds__(256) void k_attn1(const float* __restrict__ qf,
    const ushort* __restrict__ Kb, ushort* __restrict__ attn) {
  const int h = blockIdx.x, b = blockIdx.y, t = threadIdx.x;
  __shared__ ushort ks[S_ * HD_];     // 37632 B
  __shared__ float  qs[20 * HD_];     // 7680 B
  __shared__ float  ss[20 * S_];      // 15680 B
  __shared__ float  mrow[20], lrow[20];
  for (int e = t; e < S_ * HD_; e += 256) {
    int s = e / HD_, hd = e % HD_;
    ks[e] = Kb[(size_t)(b * S_ + s) * D_ + h * HD_ + hd];
  }
  const float scale = 0.1020620726f; // 1/sqrt(96)
  for (int gc = 0; gc < 5; ++gc) {
    const int g0 = gc * 20;
    __syncthreads();
    for (int e = t; e < 20 * HD_; e += 256) {
      int g = e / HD_, hd = e % HD_;
      qs[e] = qf[(size_t)(g0 + g) * D_ + h * HD_ + hd];
    }
    __syncthreads();
    for (int e = t; e < 20 * S_; e += 256) {
      int g = e / S_, s = e % S_;
      const float*  qp = &qs[g * HD_];
      const ushort* kp = &ks[s * HD_];
      float acc = 0.f;
      #pragma unroll 4
      for (int d = 0; d < HD_; d += 2) {
        float2 qv = *(const float2*)&qp[d];
        unsigned int kk = *(const unsigned int*)&kp[d];
        union { unsigned int i; float f; } l0, l1;
        l0.i = kk << 16; l1.i = kk & 0xffff0000u;
        acc += qv.x * l0.f + qv.y * l1.f;
      }
      ss[e] = acc * scale;
    }
    __syncthreads();
    if (t < 20) {
      float m = -1e30f;
      for (int s = 0; s < S_; ++s) m = fmaxf(m, ss[t * S_ + s]);
      float l = 0.f;
      for (int s = 0; s < S_; ++s) l += __expf(ss[t * S_ + s] - m);
      mrow[t] = m; lrow[t] = 1.f / l;
    }
    __syncthreads();
    for (int e = t; e < 20 * S_; e += 256) {
      int g = e / S_, s = e % S_;
      float a = __expf(ss[e] - mrow[g]) * lrow[g];
      attn[((size_t)(b * NH_ + h) * G_ + g0 + g) * S_ + s] = f2bf(a);
    }
  }
}

// ---------------- attention: ctx = attn @ V -> ctx bf16 [BG,768] -----------
// grid (NH, B), block 256. g processed in 2 chunks of 50, 4 hd per thread.
__global__ __launch_bounds__(256) void k_attn2(const ushort* __restrict__ attn,
    const ushort* __restrict__ Vb, ushort* __restrict__ ctx) {
  const int h = blockIdx.x, b = blockIdx.y, t = threadIdx.x;
  __shared__ ushort vs[S_ * HD_];     // 37632 B
  __shared__ ushort as_c[50 * S_];    // 19600 B
  for (int e = t; e < S_ * HD_; e += 256) {
    int s = e / HD_, hd = e % HD_;
    vs[e] = Vb[(size_t)(b * S_ + s) * D_ + h * HD_ + hd];
  }
  for (int gc = 0; gc < 2; ++gc) {
    const int g0 = gc * 50;
    __syncthreads();
    for (int e = t; e < 50 * S_; e += 256)
      as_c[e] = attn[((size_t)(b * NH_ + h) * G_ + g0) * S_ + e];
    __syncthreads();
    for (int e = t; e < 50 * 24; e += 256) {
      const int g = e / 24, hd0 = (e % 24) * 4;
      float a0 = 0.f, a1 = 0.f, a2 = 0.f, a3 = 0.f;
      const ushort* ar = &as_c[g * S_];
      for (int s = 0; s < S_; ++s) {
        float a = bf2f(ar[s]);
        uint2 vv = *(const uint2*)&vs[s * HD_ + hd0];
        union { unsigned int i; float f; } v0, v1, v2, v3;
        v0.i = vv.x << 16; v1.i = vv.x & 0xffff0000u;
        v2.i = vv.y << 16; v3.i = vv.y & 0xffff0000u;
        a0 += a * v0.f; a1 += a * v1.f; a2 += a * v2.f; a3 += a * v3.f;
      }
      size_t o = ((size_t)b * G_ + g0 + g) * D_ + h * HD_ + hd0;
      ctx[o] = f2bf(a0); ctx[o + 1] = f2bf(a1); ctx[o + 2] = f2bf(a2); ctx[o + 3] = f2bf(a3);
    }
  }
}

// ---------------- residual + LayerNorm -------------------------------------
// grid BG rows. resid_mod: 1 -> resid row = row%G (broadcast tgt), 0 -> row.
__global__ __launch_bounds__(256) void k_lnres(const float* __restrict__ resid, int resid_mod,
    const float* __restrict__ add, const float* __restrict__ gamma, const float* __restrict__ beta,
    float* __restrict__ outf, ushort* __restrict__ outb) {
  const int row = blockIdx.x, t = threadIdx.x;
  __shared__ float r1[256], r2[256];
  const float* rrow = resid + (size_t)(resid_mod ? (row % G_) : row) * D_;
  const float* arow = add + (size_t)row * D_;
  float y[3]; float s = 0.f, sq = 0.f;
  #pragma unroll
  for (int i = 0; i < 3; ++i) {
    int d = t + i * 256;
    float v = rrow[d] + arow[d];
    y[i] = v; s += v; sq += v * v;
  }
  r1[t] = s; r2[t] = sq; __syncthreads();
  for (int o = 128; o > 0; o >>= 1) { if (t < o) { r1[t] += r1[t + o]; r2[t] += r2[t + o]; } __syncthreads(); }
  const float mean = r1[0] * (1.f / D_);
  const float var  = r2[0] * (1.f / D_) - mean * mean;
  const float w = rsqrtf(var + 1e-5f);
  #pragma unroll
  for (int i = 0; i < 3; ++i) {
    int d = t + i * 256;
    float v = (y[i] - mean) * w * gamma[d] + beta[d];
    if (outf) outf[(size_t)row * D_ + d] = v;
    if (outb) outb[(size_t)row * D_ + d] = f2bf(v);
  }
}

// ---------------- grouped head: logits[b, g*97+f] ---------------------------
// grid (G, 4): 16 batch rows per block.
__global__ __launch_bounds__(256) void k_head(const ushort* __restrict__ h, const ushort* __restrict__ dup,
    const float* __restrict__ dup_bias, float* __restrict__ out) {
  const int g = blockIdx.x, b0 = blockIdx.y * 16, t = threadIdx.x;
  __shared__ ushort hs[16 * D_];      // 24576 B
  for (int e = t; e < 16 * D_; e += 256) {
    int bi = e / D_, d = e % D_;
    hs[e] = h[((size_t)(b0 + bi) * G_ + g) * D_ + d];
  }
  __syncthreads();
  for (int e = t; e < 16 * DF_; e += 256) {
    const int bi = e / DF_, f = e % DF_;
    const int n = g * DF_ + f;
    if (n >= NC_) continue;
    const ushort* hp = &hs[bi * D_];
    const ushort* wp = dup + (size_t)g * D_ * DF_ + f;
    float acc = 0.f;
    #pragma unroll 4
    for (int d = 0; d < D_; ++d)
      acc += bf2f(hp[d]) * bf2f(wp[(size_t)d * DF_]);
    out[(size_t)(b0 + bi) * NC_ + n] = acc + dup_bias[n];
  }
}

// ---------------------------------------------------------------------------
// workspace layout (bytes), total ~207 MB
// ---------------------------------------------------------------------------
static constexpr size_t OFF_AEMB  = 0;          // bf16 [12544,2048] = 51,380,224
static constexpr size_t OFF_ATTN  = 0;          // bf16 [512,100,196] = 20,070,400 (after embed gemm)
static constexpr size_t OFF_FF    = 0;          // bf16 [6400,2048] = 26,214,400 (after attn2)
static constexpr size_t OFF_FFO   = 26214400;   // f32  [6400,768]  = 19,660,800
static constexpr size_t OFF_WEMB  = 51380224;   // bf16 3,145,728
static constexpr size_t OFF_MEM   = 54525952;   // bf16 [12544,768] = 19,267,584
static constexpr size_t OFF_WK    = 73793536;   // 1,179,648
static constexpr size_t OFF_WV    = 74973184;   // 1,179,648
static constexpr size_t OFF_WO    = 76152832;   // 1,179,648
static constexpr size_t OFF_W1    = 77332480;   // 3,145,728
static constexpr size_t OFF_W2    = 80478208;   // 3,145,728
static constexpr size_t OFF_DUP   = 83623936;   // 14,899,200
static constexpr size_t OFF_KB    = 98523136;   // 19,267,584
static constexpr size_t OFF_VB    = 117790720;  // 19,267,584
static constexpr size_t OFF_TGT   = 137058304;  // 307,200
static constexpr size_t OFF_Q     = 137365504;  // 307,200
static constexpr size_t OFF_CTX   = 137672704;  // 9,830,400
static constexpr size_t OFF_CTXO  = 147503104;  // 19,660,800
static constexpr size_t OFF_TGT2F = 167163904;  // 19,660,800
static constexpr size_t OFF_TGT2B = 186824704;  // 9,830,400
static constexpr size_t OFF_HB    = 196655104;  // 9,830,400  (end 206,485,504)

extern "C" void kernel_launch(void* const* d_in, const int* in_sizes, int n_in,
                              void* d_out, int out_size, void* d_ws, size_t ws_size,
                              hipStream_t stream) {
  const float* x           = (const float*)d_in[0];
  const float* w_embed     = (const float*)d_in[1];
  const float* b_embed     = (const float*)d_in[2];
  const float* query_embed = (const float*)d_in[3];
  const float* wq          = (const float*)d_in[4];
  const float* bq          = (const float*)d_in[5];
  const float* wk          = (const float*)d_in[6];
  const float* bk          = (const float*)d_in[7];
  const float* wv          = (const float*)d_in[8];
  const float* bv          = (const float*)d_in[9];
  const float* wo          = (const float*)d_in[10];
  const float* bo          = (const float*)d_in[11];
  const float* g1          = (const float*)d_in[12];
  const float* be1         = (const float*)d_in[13];
  const float* g2          = (const float*)d_in[14];
  const float* be2         = (const float*)d_in[15];
  const float* g3          = (const float*)d_in[16];
  const float* be3         = (const float*)d_in[17];
  const float* w1          = (const float*)d_in[18];
  const float* bl1         = (const float*)d_in[19];
  const float* w2          = (const float*)d_in[20];
  const float* bl2         = (const float*)d_in[21];
  const float* dup_pool    = (const float*)d_in[22];
  const float* dup_bias    = (const float*)d_in[23];
  float* out = (float*)d_out;
  char* ws = (char*)d_ws;

  ushort* aemb  = (ushort*)(ws + OFF_AEMB);
  ushort* wembB = (ushort*)(ws + OFF_WEMB);
  ushort* memB  = (ushort*)(ws + OFF_MEM);
  ushort* wkB   = (ushort*)(ws + OFF_WK);
  ushort* wvB   = (ushort*)(ws + OFF_WV);
  ushort* woB   = (ushort*)(ws + OFF_WO);
  ushort* w1B   = (ushort*)(ws + OFF_W1);
  ushort* w2B   = (ushort*)(ws + OFF_W2);
  ushort* dupB  = (ushort*)(ws + OFF_DUP);
  ushort* Kb    = (ushort*)(ws + OFF_KB);
  ushort* Vb    = (ushort*)(ws + OFF_VB);
  float*  tgtF  = (float*)(ws + OFF_TGT);
  float*  qF    = (float*)(ws + OFF_Q);
  ushort* attnB = (ushort*)(ws + OFF_ATTN);
  ushort* ctxB  = (ushort*)(ws + OFF_CTX);
  float*  ctxoF = (float*)(ws + OFF_CTXO);
  float*  tgt2F = (float*)(ws + OFF_TGT2F);
  ushort* tgt2B = (ushort*)(ws + OFF_TGT2B);
  ushort* ffB   = (ushort*)(ws + OFF_FF);
  float*  ffoF  = (float*)(ws + OFF_FFO);
  ushort* hB    = (ushort*)(ws + OFF_HB);

  // 1. weight conversions to bf16
  k_cvt4<<<1024, 256, 0, stream>>>(w_embed,  wembB, D_ * CIN_ / 4);
  k_cvt4<<<1024, 256, 0, stream>>>(wk,       wkB,   D_ * D_ / 4);
  k_cvt4<<<1024, 256, 0, stream>>>(wv,       wvB,   D_ * D_ / 4);
  k_cvt4<<<1024, 256, 0, stream>>>(wo,       woB,   D_ * D_ / 4);
  k_cvt4<<<1024, 256, 0, stream>>>(w1,       w1B,   FF_ * D_ / 4);
  k_cvt4<<<1024, 256, 0, stream>>>(w2,       w2B,   D_ * FF_ / 4);
  k_cvt4<<<2048, 256, 0, stream>>>(dup_pool, dupB,  G_ * D_ * DF_ / 4);

  // 2. x transpose+convert -> A_emb [B*S, C]
  k_xpose<<<dim3(CIN_ / 32, 7, B_), 256, 0, stream>>>(x, aemb);

  // 3-4. tgt = LN(2*query_embed), q = tgt@wq^T + bq (batch-independent)
  k_tgt<<<G_, 256, 0, stream>>>(query_embed, g1, be1, tgtF);
  k_qproj<<<G_, 256, 0, stream>>>(tgtF, wq, bq, qF);

  // 5. embed GEMM + relu -> mem bf16 [12544, 768]
  k_gemm<<<dim3(D_ / 128, BS_ / 128), 256, 0, stream>>>(aemb, wembB, b_embed, nullptr, memB,
                                                        BS_, D_, CIN_, 1);
  // 6-7. K/V projections -> bf16 [12544, 768]
  k_gemm<<<dim3(D_ / 128, BS_ / 128), 256, 0, stream>>>(memB, wkB, bk, nullptr, Kb, BS_, D_, D_, 0);
  k_gemm<<<dim3(D_ / 128, BS_ / 128), 256, 0, stream>>>(memB, wvB, bv, nullptr, Vb, BS_, D_, D_, 0);

  // 8-9. attention
  k_attn1<<<dim3(NH_, B_), 256, 0, stream>>>(qF, Kb, attnB);
  k_attn2<<<dim3(NH_, B_), 256, 0, stream>>>(attnB, Vb, ctxB);

  // 10. ctx @ wo^T + bo -> fp32 [6400, 768]
  k_gemm<<<dim3(D_ / 128, BG_ / 128), 256, 0, stream>>>(ctxB, woB, bo, ctxoF, nullptr, BG_, D_, D_, 0);

  // 11. tgt2 = LN(tgt + ctxo)
  k_lnres<<<BG_, 256, 0, stream>>>(tgtF, 1, ctxoF, g2, be2, tgt2F, tgt2B);

  // 12-13. FFN
  k_gemm<<<dim3(FF_ / 128, BG_ / 128), 256, 0, stream>>>(tgt2B, w1B, bl1, nullptr, ffB, BG_, FF_, D_, 1);
  k_gemm<<<dim3(D_ / 128, BG_ / 128), 256, 0, stream>>>(ffB, w2B, bl2, ffoF, nullptr, BG_, D_, FF_, 0);

  // 14. h = LN(tgt2 + ffo) -> bf16
  k_lnres<<<BG_, 256, 0, stream>>>(tgt2F, 0, ffoF, g3, be3, nullptr, hB);

  // 15. grouped head -> logits fp32 [64, 9605]
  k_head<<<dim3(G_, 4), 256, 0, stream>>>(hB, dupB, dup_bias, out);
}

// Round 2
// 931.311 us; speedup vs baseline: 1.2618x; 1.2618x over previous
//
#include <hip/hip_runtime.h>
#include <hip/hip_bf16.h>

// ---------------------------------------------------------------------------
// MLDecoder classification head, MI355X bf16-MFMA implementation.
// B=64, C_IN=2048, H=W=14 (S=196), D=768, FF=2048, G=100, NC=9605, NH=8, HD=96
// ---------------------------------------------------------------------------

#define B_    64
#define CIN_  2048
#define S_    196
#define D_    768
#define FF_   2048
#define G_    100
#define NC_   9605
#define NH_   8
#define HD_   96
#define DF_   97
#define FP_   112          // DF_ padded to 16
#define BS_   (B_ * S_)   // 12544
#define BG_   (B_ * G_)   // 6400

typedef __bf16 bf16x8 __attribute__((ext_vector_type(8)));
typedef float  f32x4  __attribute__((ext_vector_type(4)));

__device__ __forceinline__ float bf2f(ushort u) {
  union { unsigned int i; float f; } v; v.i = ((unsigned int)u) << 16; return v.f;
}
__device__ __forceinline__ ushort f2bf(float f) {
  __hip_bfloat16 h = __float2bfloat16(f);
  return *reinterpret_cast<ushort*>(&h);
}

// async global->LDS, 16 bytes per lane. LDS target must be wave-uniform base
// + lane*16 (our staging layouts satisfy this: lds byte offset == 16*t).
__device__ __forceinline__ void gl2lds16(const ushort* g, ushort* l) {
  __builtin_amdgcn_global_load_lds((const __attribute__((address_space(1))) unsigned int*)g,
                                   (__attribute__((address_space(3))) unsigned int*)l, 16, 0, 0);
}

// ---------------- fp32 -> bf16 bulk convert (n divisible by 4) -------------
__global__ void k_cvt4(const float* __restrict__ in, ushort* __restrict__ out, int n4) {
  int i = blockIdx.x * blockDim.x + threadIdx.x;
  int stride = gridDim.x * blockDim.x;
  for (; i < n4; i += stride) {
    float4 v = ((const float4*)in)[i];
    ushort4 o;
    o.x = f2bf(v.x); o.y = f2bf(v.y); o.z = f2bf(v.z); o.w = f2bf(v.w);
    ((ushort4*)out)[i] = o;
  }
}

// ---------------- x [B][C][S] fp32 -> A_emb [B*S][C] bf16 ------------------
// grid (CIN/32, ceil(S/32)=7, B), block 256
__global__ __launch_bounds__(256) void k_xpose(const float* __restrict__ x, ushort* __restrict__ A) {
  __shared__ float tile[32][33];
  const int c0 = blockIdx.x * 32, s0 = blockIdx.y * 32, b = blockIdx.z;
  const int tx = threadIdx.x & 31, ty = threadIdx.x >> 5;   // ty in 0..7
  const float* xb = x + (size_t)b * CIN_ * S_;
  #pragma unroll
  for (int r = 0; r < 32; r += 8) {
    int c = c0 + ty + r, s = s0 + tx;
    tile[ty + r][tx] = (s < S_) ? xb[(size_t)c * S_ + s] : 0.f;
  }
  __syncthreads();
  #pragma unroll
  for (int r = 0; r < 32; r += 8) {
    int s = s0 + ty + r, c = c0 + tx;
    if (s < S_) A[((size_t)(b * S_ + s)) * CIN_ + c] = f2bf(tile[tx][ty + r]);
  }
}

// ------- dup_pool [g][d=768][f=97] fp32 -> dupT [g][f=112][d=768] bf16 -----
// zero-pads f rows 97..111. grid (4, 24, 100), block 256 (32x8 tile engine)
__global__ __launch_bounds__(256) void k_dupT(const float* __restrict__ dup, ushort* __restrict__ dupT) {
  __shared__ float tile[32][33];
  const int f0 = blockIdx.x * 32, d0 = blockIdx.y * 32, g = blockIdx.z;
  const int tx = threadIdx.x & 31, ty = threadIdx.x >> 5;
  #pragma unroll
  for (int r = 0; r < 32; r += 8) {
    int d = d0 + ty + r, f = f0 + tx;
    tile[ty + r][tx] = (f < DF_) ? dup[(size_t)g * D_ * DF_ + (size_t)d * DF_ + f] : 0.f;
  }
  __syncthreads();
  #pragma unroll
  for (int r = 0; r < 32; r += 8) {
    int f = f0 + ty + r, d = d0 + tx;
    if (f < FP_) dupT[((size_t)g * FP_ + f) * D_ + d] = f2bf(tile[tx][ty + r]);
  }
}

// ---------------- tgt = LN(2*query_embed)*g1 + be1  [G,768] fp32 -----------
__global__ __launch_bounds__(256) void k_tgt(const float* __restrict__ qe,
    const float* __restrict__ g1, const float* __restrict__ be1, float* __restrict__ tgt) {
  const int g = blockIdx.x, t = threadIdx.x;
  __shared__ float r1[256], r2[256];
  float y[3]; float s = 0.f, sq = 0.f;
  const float* row = qe + (size_t)g * D_;
  #pragma unroll
  for (int i = 0; i < 3; ++i) { float v = 2.f * row[t + i * 256]; y[i] = v; s += v; sq += v * v; }
  r1[t] = s; r2[t] = sq; __syncthreads();
  for (int o = 128; o > 0; o >>= 1) { if (t < o) { r1[t] += r1[t + o]; r2[t] += r2[t + o]; } __syncthreads(); }
  const float mean = r1[0] * (1.f / D_);
  const float var  = r2[0] * (1.f / D_) - mean * mean;
  const float w = rsqrtf(var + 1e-5f);
  #pragma unroll
  for (int i = 0; i < 3; ++i) { int d = t + i * 256; tgt[(size_t)g * D_ + d] = (y[i] - mean) * w * g1[d] + be1[d]; }
}

// ---------------- q = tgt @ wq^T + bq   [G,768] fp32 -----------------------
__global__ __launch_bounds__(256) void k_qproj(const float* __restrict__ tgt,
    const float* __restrict__ wq, const float* __restrict__ bq, float* __restrict__ q) {
  const int g = blockIdx.x, t = threadIdx.x;
  __shared__ float ts[D_];
  for (int d = t; d < D_; d += 256) ts[d] = tgt[(size_t)g * D_ + d];
  __syncthreads();
  for (int e = t; e < D_; e += 256) {
    const float* w = wq + (size_t)e * D_;
    float acc = bq[e];
    for (int d = 0; d < D_; d += 4) {
      float4 wv = *(const float4*)&w[d];
      acc += ts[d] * wv.x + ts[d + 1] * wv.y + ts[d + 2] * wv.z + ts[d + 3] * wv.w;
    }
    q[(size_t)g * D_ + e] = acc;
  }
}

// ---------------- bf16 MFMA GEMM: C[M,N] = A[M,K] * B[N,K]^T + bias --------
// 128x128 tile, BK=32, 256 threads (4 waves, each 64x64 = 4x4 of 16x16x32)
// staging via global_load_lds width-16 (m97 pattern).
__global__ __launch_bounds__(256) void k_gemm(const ushort* __restrict__ A, const ushort* __restrict__ B,
    const float* __restrict__ bias, float* __restrict__ Cf, ushort* __restrict__ Cb,
    int M, int N, int K, int relu) {
  __shared__ ushort As[128 * 32];
  __shared__ ushort Bs[128 * 32];
  const int t = threadIdx.x;
  const int m0 = blockIdx.y * 128, n0 = blockIdx.x * 128;
  const int lane = t & 63, wave = t >> 6;
  const int quad = lane >> 4, lrow = lane & 15;
  const int wr = (wave >> 1) * 64, wc = (wave & 1) * 64;
  const int srow = t >> 2, scol = (t & 3) * 8;
  f32x4 acc[4][4] = {};
  for (int k0 = 0; k0 < K; k0 += 32) {
    const ushort* ag = A + (size_t)(m0 + srow) * K + k0 + scol;
    const ushort* bg = B + (size_t)(n0 + srow) * K + k0 + scol;
    gl2lds16(ag,                    &As[srow * 32 + scol]);
    gl2lds16(ag + (size_t)64 * K,   &As[(srow + 64) * 32 + scol]);
    gl2lds16(bg,                    &Bs[srow * 32 + scol]);
    gl2lds16(bg + (size_t)64 * K,   &Bs[(srow + 64) * 32 + scol]);
    __syncthreads();
    bf16x8 af[4], bfr[4];
    #pragma unroll
    for (int i = 0; i < 4; ++i) af[i] = *(const bf16x8*)&As[(wr + i * 16 + lrow) * 32 + quad * 8];
    #pragma unroll
    for (int j = 0; j < 4; ++j) bfr[j] = *(const bf16x8*)&Bs[(wc + j * 16 + lrow) * 32 + quad * 8];
    #pragma unroll
    for (int i = 0; i < 4; ++i)
      #pragma unroll
      for (int j = 0; j < 4; ++j)
        acc[i][j] = __builtin_amdgcn_mfma_f32_16x16x32_bf16(af[i], bfr[j], acc[i][j], 0, 0, 0);
    __syncthreads();
  }
  #pragma unroll
  for (int i = 0; i < 4; ++i) {
    #pragma unroll
    for (int j = 0; j < 4; ++j) {
      const int gcol = n0 + wc + j * 16 + lrow;
      const float bv = bias ? bias[gcol] : 0.f;
      #pragma unroll
      for (int r = 0; r < 4; ++r) {
        const int grow = m0 + wr + i * 16 + quad * 4 + r;
        float v = acc[i][j][r] + bv;
        if (relu) v = fmaxf(v, 0.f);
        if (Cf) Cf[(size_t)grow * N + gcol] = v;
        else    Cb[(size_t)grow * N + gcol] = f2bf(v);
      }
    }
  }
}

// ---------------- attention: scores + softmax -> attn bf16 -----------------
// grid (NH, B), block 256. g processed in 5 chunks of 20.
__global__ __launch_bounds__(256) void k_attn1(const float* __restrict__ qf,
    const ushort* __restrict__ Kb, ushort* __restrict__ attn) {
  const int h = blockIdx.x, b = blockIdx.y, t = threadIdx.x;
  __shared__ ushort ks[S_ * HD_];     // 37632 B
  __shared__ float  qs[20 * HD_];     // 7680 B
  __shared__ float  ss[20 * S_];      // 15680 B
  __shared__ float  mrow[20], lrow[20];
  for (int e = t; e < S_ * HD_; e += 256) {
    int s = e / HD_, hd = e % HD_;
    ks[e] = Kb[(size_t)(b * S_ + s) * D_ + h * HD_ + hd];
  }
  const float scale = 0.1020620726f; // 1/sqrt(96)
  for (int gc = 0; gc < 5; ++gc) {
    const int g0 = gc * 20;
    __syncthreads();
    for (int e = t; e < 20 * HD_; e += 256) {
      int g = e / HD_, hd = e % HD_;
      qs[e] = qf[(size_t)(g0 + g) * D_ + h * HD_ + hd];
    }
    __syncthreads();
    for (int e = t; e < 20 * S_; e += 256) {
      int g = e / S_, s = e % S_;
      const float*  qp = &qs[g * HD_];
      const ushort* kp = &ks[s * HD_];
      float acc = 0.f;
      #pragma unroll 4
      for (int d = 0; d < HD_; d += 2) {
        float2 qv = *(const float2*)&qp[d];
        unsigned int kk = *(const unsigned int*)&kp[d];
        union { unsigned int i; float f; } l0, l1;
        l0.i = kk << 16; l1.i = kk & 0xffff0000u;
        acc += qv.x * l0.f + qv.y * l1.f;
      }
      ss[e] = acc * scale;
    }
    __syncthreads();
    if (t < 20) {
      float m = -1e30f;
      for (int s = 0; s < S_; ++s) m = fmaxf(m, ss[t * S_ + s]);
      float l = 0.f;
      for (int s = 0; s < S_; ++s) l += __expf(ss[t * S_ + s] - m);
      mrow[t] = m; lrow[t] = 1.f / l;
    }
    __syncthreads();
    for (int e = t; e < 20 * S_; e += 256) {
      int g = e / S_, s = e % S_;
      float a = __expf(ss[e] - mrow[g]) * lrow[g];
      attn[((size_t)(b * NH_ + h) * G_ + g0 + g) * S_ + s] = f2bf(a);
    }
  }
}

// ---------------- attention: ctx = attn @ V -> ctx bf16 [BG,768] -----------
// grid (NH, B), block 256. g processed in 2 chunks of 50, 4 hd per thread.
__global__ __launch_bounds__(256) void k_attn2(const ushort* __restrict__ attn,
    const ushort* __restrict__ Vb, ushort* __restrict__ ctx) {
  const int h = blockIdx.x, b = blockIdx.y, t = threadIdx.x;
  __shared__ ushort vs[S_ * HD_];     // 37632 B
  __shared__ ushort as_c[50 * S_];    // 19600 B
  for (int e = t; e < S_ * HD_; e += 256) {
    int s = e / HD_, hd = e % HD_;
    vs[e] = Vb[(size_t)(b * S_ + s) * D_ + h * HD_ + hd];
  }
  for (int gc = 0; gc < 2; ++gc) {
    const int g0 = gc * 50;
    __syncthreads();
    for (int e = t; e < 50 * S_; e += 256)
      as_c[e] = attn[((size_t)(b * NH_ + h) * G_ + g0) * S_ + e];
    __syncthreads();
    for (int e = t; e < 50 * 24; e += 256) {
      const int g = e / 24, hd0 = (e % 24) * 4;
      float a0 = 0.f, a1 = 0.f, a2 = 0.f, a3 = 0.f;
      const ushort* ar = &as_c[g * S_];
      for (int s = 0; s < S_; ++s) {
        float a = bf2f(ar[s]);
        uint2 vv = *(const uint2*)&vs[s * HD_ + hd0];
        union { unsigned int i; float f; } v0, v1, v2, v3;
        v0.i = vv.x << 16; v1.i = vv.x & 0xffff0000u;
        v2.i = vv.y << 16; v3.i = vv.y & 0xffff0000u;
        a0 += a * v0.f; a1 += a * v1.f; a2 += a * v2.f; a3 += a * v3.f;
      }
      size_t o = ((size_t)b * G_ + g0 + g) * D_ + h * HD_ + hd0;
      ctx[o] = f2bf(a0); ctx[o + 1] = f2bf(a1); ctx[o + 2] = f2bf(a2); ctx[o + 3] = f2bf(a3);
    }
  }
}

// ---------------- residual + LayerNorm -------------------------------------
// grid BG rows. resid_mod: 1 -> resid row = row%G (broadcast tgt), 0 -> row.
__global__ __launch_bounds__(256) void k_lnres(const float* __restrict__ resid, int resid_mod,
    const float* __restrict__ add, const float* __restrict__ gamma, const float* __restrict__ beta,
    float* __restrict__ outf, ushort* __restrict__ outb) {
  const int row = blockIdx.x, t = threadIdx.x;
  __shared__ float r1[256], r2[256];
  const float* rrow = resid + (size_t)(resid_mod ? (row % G_) : row) * D_;
  const float* arow = add + (size_t)row * D_;
  float y[3]; float s = 0.f, sq = 0.f;
  #pragma unroll
  for (int i = 0; i < 3; ++i) {
    int d = t + i * 256;
    float v = rrow[d] + arow[d];
    y[i] = v; s += v; sq += v * v;
  }
  r1[t] = s; r2[t] = sq; __syncthreads();
  for (int o = 128; o > 0; o >>= 1) { if (t < o) { r1[t] += r1[t + o]; r2[t] += r2[t + o]; } __syncthreads(); }
  const float mean = r1[0] * (1.f / D_);
  const float var  = r2[0] * (1.f / D_) - mean * mean;
  const float w = rsqrtf(var + 1e-5f);
  #pragma unroll
  for (int i = 0; i < 3; ++i) {
    int d = t + i * 256;
    float v = (y[i] - mean) * w * gamma[d] + beta[d];
    if (outf) outf[(size_t)row * D_ + d] = v;
    if (outb) outb[(size_t)row * D_ + d] = f2bf(v);
  }
}

// ---------------- grouped head via MFMA ------------------------------------
// one block per group g. M=64 (batch), N=112 (f padded), K=768.
// 4 waves: wave w owns batch rows 16w..16w+15, all 7 N-tiles.
__global__ __launch_bounds__(256) void k_head2(const ushort* __restrict__ h,
    const ushort* __restrict__ dupT, const float* __restrict__ dup_bias, float* __restrict__ out) {
  __shared__ ushort As[64 * 32];    // 4 KB
  __shared__ ushort Bs[FP_ * 32];   // 7 KB
  const int g = blockIdx.x, t = threadIdx.x;
  const int lane = t & 63, wave = t >> 6;
  const int quad = lane >> 4, lrow = lane & 15;
  const int srow = t >> 2, scol = (t & 3) * 8;
  f32x4 acc[7] = {};
  for (int k0 = 0; k0 < D_; k0 += 32) {
    // A: 64 rows (batch) x 32 k. lds byte offset = 16*t (wave-contiguous).
    gl2lds16(h + ((size_t)srow * G_ + g) * D_ + k0 + scol, &As[srow * 32 + scol]);
    // B: 112 rows x 32 k = 448 chunks; waves 0-2 take the second round.
    for (int i = t; i < FP_ * 4; i += 256) {
      const int row = i >> 2, col = (i & 3) * 8;
      gl2lds16(dupT + ((size_t)g * FP_ + row) * D_ + k0 + col, &Bs[row * 32 + col]);
    }
    __syncthreads();
    bf16x8 af = *(const bf16x8*)&As[(wave * 16 + lrow) * 32 + quad * 8];
    #pragma unroll
    for (int j = 0; j < 7; ++j) {
      bf16x8 bfr = *(const bf16x8*)&Bs[(j * 16 + lrow) * 32 + quad * 8];
      acc[j] = __builtin_amdgcn_mfma_f32_16x16x32_bf16(af, bfr, acc[j], 0, 0, 0);
    }
    __syncthreads();
  }
  #pragma unroll
  for (int j = 0; j < 7; ++j) {
    const int f = j * 16 + lrow;
    if (f >= DF_) continue;
    const int n = g * DF_ + f;
    if (n >= NC_) continue;
    const float bv = dup_bias[n];
    #pragma unroll
    for (int r = 0; r < 4; ++r) {
      const int b = wave * 16 + quad * 4 + r;
      out[(size_t)b * NC_ + n] = acc[j][r] + bv;
    }
  }
}

// ---------------------------------------------------------------------------
// workspace layout (bytes)
// ---------------------------------------------------------------------------
static constexpr size_t OFF_AEMB  = 0;          // bf16 [12544,2048] = 51,380,224
static constexpr size_t OFF_ATTN  = 0;          // bf16 [512,100,196] = 20,070,400 (after embed gemm)
static constexpr size_t OFF_FF    = 0;          // bf16 [6400,2048] = 26,214,400 (after attn2)
static constexpr size_t OFF_FFO   = 26214400;   // f32  [6400,768]  = 19,660,800
static constexpr size_t OFF_WEMB  = 51380224;   // bf16 3,145,728
static constexpr size_t OFF_MEM   = 54525952;   // bf16 [12544,768] = 19,267,584
static constexpr size_t OFF_WK    = 73793536;   // 1,179,648
static constexpr size_t OFF_WV    = 74973184;   // 1,179,648
static constexpr size_t OFF_WO    = 76152832;   // 1,179,648
static constexpr size_t OFF_W1    = 77332480;   // 3,145,728
static constexpr size_t OFF_W2    = 80478208;   // 3,145,728
static constexpr size_t OFF_DUP   = 83623936;   // bf16 [100,112,768] = 17,203,200
static constexpr size_t OFF_KB    = 100827136;  // 19,267,584
static constexpr size_t OFF_VB    = 120094720;  // 19,267,584
static constexpr size_t OFF_TGT   = 139362304;  // 307,200
static constexpr size_t OFF_Q     = 139669504;  // 307,200
static constexpr size_t OFF_CTX   = 139976704;  // 9,830,400
static constexpr size_t OFF_CTXO  = 149807104;  // 19,660,800
static constexpr size_t OFF_TGT2F = 169467904;  // 19,660,800
static constexpr size_t OFF_TGT2B = 189128704;  // 9,830,400
static constexpr size_t OFF_HB    = 198959104;  // 9,830,400  (end 208,789,504)

extern "C" void kernel_launch(void* const* d_in, const int* in_sizes, int n_in,
                              void* d_out, int out_size, void* d_ws, size_t ws_size,
                              hipStream_t stream) {
  const float* x           = (const float*)d_in[0];
  const float* w_embed     = (const float*)d_in[1];
  const float* b_embed     = (const float*)d_in[2];
  const float* query_embed = (const float*)d_in[3];
  const float* wq          = (const float*)d_in[4];
  const float* bq          = (const float*)d_in[5];
  const float* wk          = (const float*)d_in[6];
  const float* bk          = (const float*)d_in[7];
  const float* wv          = (const float*)d_in[8];
  const float* bv          = (const float*)d_in[9];
  const float* wo          = (const float*)d_in[10];
  const float* bo          = (const float*)d_in[11];
  const float* g1          = (const float*)d_in[12];
  const float* be1         = (const float*)d_in[13];
  const float* g2          = (const float*)d_in[14];
  const float* be2         = (const float*)d_in[15];
  const float* g3          = (const float*)d_in[16];
  const float* be3         = (const float*)d_in[17];
  const float* w1          = (const float*)d_in[18];
  const float* bl1         = (const float*)d_in[19];
  const float* w2          = (const float*)d_in[20];
  const float* bl2         = (const float*)d_in[21];
  const float* dup_pool    = (const float*)d_in[22];
  const float* dup_bias    = (const float*)d_in[23];
  float* out = (float*)d_out;
  char* ws = (char*)d_ws;

  ushort* aemb  = (ushort*)(ws + OFF_AEMB);
  ushort* wembB = (ushort*)(ws + OFF_WEMB);
  ushort* memB  = (ushort*)(ws + OFF_MEM);
  ushort* wkB   = (ushort*)(ws + OFF_WK);
  ushort* wvB   = (ushort*)(ws + OFF_WV);
  ushort* woB   = (ushort*)(ws + OFF_WO);
  ushort* w1B   = (ushort*)(ws + OFF_W1);
  ushort* w2B   = (ushort*)(ws + OFF_W2);
  ushort* dupT  = (ushort*)(ws + OFF_DUP);
  ushort* Kb    = (ushort*)(ws + OFF_KB);
  ushort* Vb    = (ushort*)(ws + OFF_VB);
  float*  tgtF  = (float*)(ws + OFF_TGT);
  float*  qF    = (float*)(ws + OFF_Q);
  ushort* attnB = (ushort*)(ws + OFF_ATTN);
  ushort* ctxB  = (ushort*)(ws + OFF_CTX);
  float*  ctxoF = (float*)(ws + OFF_CTXO);
  float*  tgt2F = (float*)(ws + OFF_TGT2F);
  ushort* tgt2B = (ushort*)(ws + OFF_TGT2B);
  ushort* ffB   = (ushort*)(ws + OFF_FF);
  float*  ffoF  = (float*)(ws + OFF_FFO);
  ushort* hB    = (ushort*)(ws + OFF_HB);

  // 1. weight conversions to bf16 (+ dup transpose)
  k_cvt4<<<1024, 256, 0, stream>>>(w_embed,  wembB, D_ * CIN_ / 4);
  k_cvt4<<<1024, 256, 0, stream>>>(wk,       wkB,   D_ * D_ / 4);
  k_cvt4<<<1024, 256, 0, stream>>>(wv,       wvB,   D_ * D_ / 4);
  k_cvt4<<<1024, 256, 0, stream>>>(wo,       woB,   D_ * D_ / 4);
  k_cvt4<<<1024, 256, 0, stream>>>(w1,       w1B,   FF_ * D_ / 4);
  k_cvt4<<<1024, 256, 0, stream>>>(w2,       w2B,   D_ * FF_ / 4);
  k_dupT<<<dim3(4, 24, G_), 256, 0, stream>>>(dup_pool, dupT);

  // 2. x transpose+convert -> A_emb [B*S, C]
  k_xpose<<<dim3(CIN_ / 32, 7, B_), 256, 0, stream>>>(x, aemb);

  // 3-4. tgt = LN(2*query_embed), q = tgt@wq^T + bq (batch-independent)
  k_tgt<<<G_, 256, 0, stream>>>(query_embed, g1, be1, tgtF);
  k_qproj<<<G_, 256, 0, stream>>>(tgtF, wq, bq, qF);

  // 5. embed GEMM + relu -> mem bf16 [12544, 768]
  k_gemm<<<dim3(D_ / 128, BS_ / 128), 256, 0, stream>>>(aemb, wembB, b_embed, nullptr, memB,
                                                        BS_, D_, CIN_, 1);
  // 6-7. K/V projections -> bf16 [12544, 768]
  k_gemm<<<dim3(D_ / 128, BS_ / 128), 256, 0, stream>>>(memB, wkB, bk, nullptr, Kb, BS_, D_, D_, 0);
  k_gemm<<<dim3(D_ / 128, BS_ / 128), 256, 0, stream>>>(memB, wvB, bv, nullptr, Vb, BS_, D_, D_, 0);

  // 8-9. attention
  k_attn1<<<dim3(NH_, B_), 256, 0, stream>>>(qF, Kb, attnB);
  k_attn2<<<dim3(NH_, B_), 256, 0, stream>>>(attnB, Vb, ctxB);

  // 10. ctx @ wo^T + bo -> fp32 [6400, 768]
  k_gemm<<<dim3(D_ / 128, BG_ / 128), 256, 0, stream>>>(ctxB, woB, bo, ctxoF, nullptr, BG_, D_, D_, 0);

  // 11. tgt2 = LN(tgt + ctxo)
  k_lnres<<<BG_, 256, 0, stream>>>(tgtF, 1, ctxoF, g2, be2, tgt2F, tgt2B);

  // 12-13. FFN
  k_gemm<<<dim3(FF_ / 128, BG_ / 128), 256, 0, stream>>>(tgt2B, w1B, bl1, nullptr, ffB, BG_, FF_, D_, 1);
  k_gemm<<<dim3(D_ / 128, BG_ / 128), 256, 0, stream>>>(ffB, w2B, bl2, ffoF, nullptr, BG_, D_, FF_, 0);

  // 14. h = LN(tgt2 + ffo) -> bf16
  k_lnres<<<BG_, 256, 0, stream>>>(tgt2F, 0, ffoF, g3, be3, nullptr, hB);

  // 15. grouped head -> logits fp32 [64, 9605] via MFMA
  k_head2<<<G_, 256, 0, stream>>>(hB, dupT, dup_bias, out);
}

// Round 3
// 700.347 us; speedup vs baseline: 1.6779x; 1.3298x over previous
//
#include <hip/hip_runtime.h>
#include <hip/hip_bf16.h>

// ---------------------------------------------------------------------------
// MLDecoder classification head, MI355X bf16-MFMA implementation.
// B=64, C_IN=2048, H=W=14 (S=196), D=768, FF=2048, G=100, NC=9605, NH=8, HD=96
// ---------------------------------------------------------------------------

#define B_    64
#define CIN_  2048
#define S_    196
#define D_    768
#define FF_   2048
#define G_    100
#define NC_   9605
#define NH_   8
#define HD_   96
#define DF_   97
#define FP_   112          // DF_ padded to 16
#define GP_   112          // G padded to 16
#define SP_   224          // S padded to 32 (7 K-steps) for P / V^T
#define BS_   (B_ * S_)   // 12544
#define BG_   (B_ * G_)   // 6400

typedef __bf16 bf16x8 __attribute__((ext_vector_type(8)));
typedef float  f32x4  __attribute__((ext_vector_type(4)));

__device__ __forceinline__ float bf2f(ushort u) {
  union { unsigned int i; float f; } v; v.i = ((unsigned int)u) << 16; return v.f;
}
__device__ __forceinline__ ushort f2bf(float f) {
  __hip_bfloat16 h = __float2bfloat16(f);
  return *reinterpret_cast<ushort*>(&h);
}

// async global->LDS, 16 bytes per lane. LDS target must be wave-uniform base
// + lane*16 (our staging layouts satisfy this: lds byte offset == 16*i, i linear in t).
__device__ __forceinline__ void gl2lds16(const ushort* g, ushort* l) {
  __builtin_amdgcn_global_load_lds((const __attribute__((address_space(1))) unsigned int*)g,
                                   (__attribute__((address_space(3))) unsigned int*)l, 16, 0, 0);
}

// ---------------- fp32 -> bf16 bulk convert (n divisible by 4) -------------
__global__ void k_cvt4(const float* __restrict__ in, ushort* __restrict__ out, int n4) {
  int i = blockIdx.x * blockDim.x + threadIdx.x;
  int stride = gridDim.x * blockDim.x;
  for (; i < n4; i += stride) {
    float4 v = ((const float4*)in)[i];
    ushort4 o;
    o.x = f2bf(v.x); o.y = f2bf(v.y); o.z = f2bf(v.z); o.w = f2bf(v.w);
    ((ushort4*)out)[i] = o;
  }
}

// ---------------- x [B][C][S] fp32 -> A_emb [B*S][C] bf16 ------------------
// grid (CIN/32, ceil(S/32)=7, B), block 256
__global__ __launch_bounds__(256) void k_xpose(const float* __restrict__ x, ushort* __restrict__ A) {
  __shared__ float tile[32][33];
  const int c0 = blockIdx.x * 32, s0 = blockIdx.y * 32, b = blockIdx.z;
  const int tx = threadIdx.x & 31, ty = threadIdx.x >> 5;   // ty in 0..7
  const float* xb = x + (size_t)b * CIN_ * S_;
  #pragma unroll
  for (int r = 0; r < 32; r += 8) {
    int c = c0 + ty + r, s = s0 + tx;
    tile[ty + r][tx] = (s < S_) ? xb[(size_t)c * S_ + s] : 0.f;
  }
  __syncthreads();
  #pragma unroll
  for (int r = 0; r < 32; r += 8) {
    int s = s0 + ty + r, c = c0 + tx;
    if (s < S_) A[((size_t)(b * S_ + s)) * CIN_ + c] = f2bf(tile[tx][ty + r]);
  }
}

// ------- dup_pool [g][d=768][f=97] fp32 -> dupT [g][f=112][d=768] bf16 -----
__global__ __launch_bounds__(256) void k_dupT(const float* __restrict__ dup, ushort* __restrict__ dupT) {
  __shared__ float tile[32][33];
  const int f0 = blockIdx.x * 32, d0 = blockIdx.y * 32, g = blockIdx.z;
  const int tx = threadIdx.x & 31, ty = threadIdx.x >> 5;
  #pragma unroll
  for (int r = 0; r < 32; r += 8) {
    int d = d0 + ty + r, f = f0 + tx;
    tile[ty + r][tx] = (f < DF_) ? dup[(size_t)g * D_ * DF_ + (size_t)d * DF_ + f] : 0.f;
  }
  __syncthreads();
  #pragma unroll
  for (int r = 0; r < 32; r += 8) {
    int f = f0 + ty + r, d = d0 + tx;
    if (f < FP_) dupT[((size_t)g * FP_ + f) * D_ + d] = f2bf(tile[tx][ty + r]);
  }
}

// ------- Vb [(b,s)][768] bf16 -> VbT [(b,h)][96][224] bf16, s zero-padded --
// grid (7, 3, 512), block 256
__global__ __launch_bounds__(256) void k_vT(const ushort* __restrict__ Vb, ushort* __restrict__ VbT) {
  __shared__ ushort tile[32][33];
  const int s0 = blockIdx.x * 32, d0 = blockIdx.y * 32, bh = blockIdx.z;
  const int b = bh >> 3, h = bh & 7;
  const int tx = threadIdx.x & 31, ty = threadIdx.x >> 5;
  #pragma unroll
  for (int r = 0; r < 32; r += 8) {
    int s = s0 + ty + r, d = d0 + tx;
    tile[ty + r][tx] = (s < S_) ? Vb[((size_t)(b * S_ + s)) * D_ + h * HD_ + d] : (ushort)0;
  }
  __syncthreads();
  #pragma unroll
  for (int r = 0; r < 32; r += 8) {
    int d = d0 + ty + r, s = s0 + tx;
    VbT[((size_t)bh * HD_ + d) * SP_ + s] = tile[tx][ty + r];
  }
}

// ---------------- tgt = LN(2*query_embed)*g1 + be1  [G,768] fp32 -----------
__global__ __launch_bounds__(256) void k_tgt(const float* __restrict__ qe,
    const float* __restrict__ g1, const float* __restrict__ be1, float* __restrict__ tgt) {
  const int g = blockIdx.x, t = threadIdx.x;
  __shared__ float r1[256], r2[256];
  float y[3]; float s = 0.f, sq = 0.f;
  const float* row = qe + (size_t)g * D_;
  #pragma unroll
  for (int i = 0; i < 3; ++i) { float v = 2.f * row[t + i * 256]; y[i] = v; s += v; sq += v * v; }
  r1[t] = s; r2[t] = sq; __syncthreads();
  for (int o = 128; o > 0; o >>= 1) { if (t < o) { r1[t] += r1[t + o]; r2[t] += r2[t + o]; } __syncthreads(); }
  const float mean = r1[0] * (1.f / D_);
  const float var  = r2[0] * (1.f / D_) - mean * mean;
  const float w = rsqrtf(var + 1e-5f);
  #pragma unroll
  for (int i = 0; i < 3; ++i) { int d = t + i * 256; tgt[(size_t)g * D_ + d] = (y[i] - mean) * w * g1[d] + be1[d]; }
}

// ---------------- q = tgt @ wq^T + bq   [112,768] bf16 (rows>=100 zero) ----
__global__ __launch_bounds__(256) void k_qproj(const float* __restrict__ tgt,
    const float* __restrict__ wq, const float* __restrict__ bq, ushort* __restrict__ q) {
  const int g = blockIdx.x, t = threadIdx.x;
  if (g >= G_) {
    for (int e = t; e < D_; e += 256) q[(size_t)g * D_ + e] = 0;
    return;
  }
  __shared__ float ts[D_];
  for (int d = t; d < D_; d += 256) ts[d] = tgt[(size_t)g * D_ + d];
  __syncthreads();
  for (int e = t; e < D_; e += 256) {
    const float* w = wq + (size_t)e * D_;
    float acc = bq[e];
    for (int d = 0; d < D_; d += 4) {
      float4 wv = *(const float4*)&w[d];
      acc += ts[d] * wv.x + ts[d + 1] * wv.y + ts[d + 2] * wv.z + ts[d + 3] * wv.w;
    }
    q[(size_t)g * D_ + e] = f2bf(acc);
  }
}

// ---------------- bf16 MFMA GEMM: C[M,N] = A[M,K] * B[N,K]^T + bias --------
__global__ __launch_bounds__(256) void k_gemm(const ushort* __restrict__ A, const ushort* __restrict__ B,
    const float* __restrict__ bias, float* __restrict__ Cf, ushort* __restrict__ Cb,
    int M, int N, int K, int relu) {
  __shared__ ushort As[128 * 32];
  __shared__ ushort Bs[128 * 32];
  const int t = threadIdx.x;
  const int m0 = blockIdx.y * 128, n0 = blockIdx.x * 128;
  const int lane = t & 63, wave = t >> 6;
  const int quad = lane >> 4, lrow = lane & 15;
  const int wr = (wave >> 1) * 64, wc = (wave & 1) * 64;
  const int srow = t >> 2, scol = (t & 3) * 8;
  f32x4 acc[4][4] = {};
  for (int k0 = 0; k0 < K; k0 += 32) {
    const ushort* ag = A + (size_t)(m0 + srow) * K + k0 + scol;
    const ushort* bg = B + (size_t)(n0 + srow) * K + k0 + scol;
    gl2lds16(ag,                    &As[srow * 32 + scol]);
    gl2lds16(ag + (size_t)64 * K,   &As[(srow + 64) * 32 + scol]);
    gl2lds16(bg,                    &Bs[srow * 32 + scol]);
    gl2lds16(bg + (size_t)64 * K,   &Bs[(srow + 64) * 32 + scol]);
    __syncthreads();
    bf16x8 af[4], bfr[4];
    #pragma unroll
    for (int i = 0; i < 4; ++i) af[i] = *(const bf16x8*)&As[(wr + i * 16 + lrow) * 32 + quad * 8];
    #pragma unroll
    for (int j = 0; j < 4; ++j) bfr[j] = *(const bf16x8*)&Bs[(wc + j * 16 + lrow) * 32 + quad * 8];
    #pragma unroll
    for (int i = 0; i < 4; ++i)
      #pragma unroll
      for (int j = 0; j < 4; ++j)
        acc[i][j] = __builtin_amdgcn_mfma_f32_16x16x32_bf16(af[i], bfr[j], acc[i][j], 0, 0, 0);
    __syncthreads();
  }
  #pragma unroll
  for (int i = 0; i < 4; ++i) {
    #pragma unroll
    for (int j = 0; j < 4; ++j) {
      const int gcol = n0 + wc + j * 16 + lrow;
      const float bv = bias ? bias[gcol] : 0.f;
      #pragma unroll
      for (int r = 0; r < 4; ++r) {
        const int grow = m0 + wr + i * 16 + quad * 4 + r;
        float v = acc[i][j][r] + bv;
        if (relu) v = fmaxf(v, 0.f);
        if (Cf) Cf[(size_t)grow * N + gcol] = v;
        else    Cb[(size_t)grow * N + gcol] = f2bf(v);
      }
    }
  }
}

// ---------------- scores + in-register softmax -> P bf16 [bh][112][224] ----
// grid (NH, B), block 256. MFMA QK^T, K staged via global_load_lds.
__global__ __launch_bounds__(256) void k_scores(const ushort* __restrict__ qB,
    const ushort* __restrict__ Kb, ushort* __restrict__ attnP) {
  __shared__ ushort Ks[208 * HD_];   // 39936 B
  const int h = blockIdx.x, b = blockIdx.y, t = threadIdx.x;
  const int bh = b * NH_ + h;
  const int lane = t & 63, wave = t >> 6;
  const int quad = lane >> 4, c = lane & 15;
  // stage K rows 0..207 (rows >=196 read in-bounds garbage, masked below)
  for (int i = t; i < 208 * 12; i += 256) {
    int r = i / 12, col = (i % 12) * 8;
    gl2lds16(Kb + ((size_t)(b * S_ + r)) * D_ + h * HD_ + col, &Ks[i * 8]);
  }
  __syncthreads();
  const float scale = 0.1020620726f;  // 1/sqrt(96)
  for (int ii = wave; ii < 7; ii += 4) {
    f32x4 acc[13] = {};
    bf16x8 af[3];
    #pragma unroll
    for (int ks = 0; ks < 3; ++ks)
      af[ks] = *(const bf16x8*)(qB + ((size_t)(ii * 16 + c)) * D_ + h * HD_ + ks * 32 + quad * 8);
    #pragma unroll
    for (int j = 0; j < 13; ++j) {
      #pragma unroll
      for (int ks = 0; ks < 3; ++ks) {
        bf16x8 bf = *(const bf16x8*)&Ks[(j * 16 + c) * HD_ + ks * 32 + quad * 8];
        acc[j] = __builtin_amdgcn_mfma_f32_16x16x32_bf16(af[ks], bf, acc[j], 0, 0, 0);
      }
    }
    // softmax: row g = ii*16 + quad*4 + r lives in the 16-lane cluster (c = s-offset)
    float m[4] = {-1e30f, -1e30f, -1e30f, -1e30f};
    #pragma unroll
    for (int j = 0; j < 13; ++j)
      #pragma unroll
      for (int r = 0; r < 4; ++r) {
        float v = acc[j][r] * scale;
        if (j == 12 && c >= 4) v = -1e30f;   // mask padded s in 196..207
        acc[j][r] = v;
        m[r] = fmaxf(m[r], v);
      }
    #pragma unroll
    for (int r = 0; r < 4; ++r) {
      m[r] = fmaxf(m[r], __shfl_xor(m[r], 1));
      m[r] = fmaxf(m[r], __shfl_xor(m[r], 2));
      m[r] = fmaxf(m[r], __shfl_xor(m[r], 4));
      m[r] = fmaxf(m[r], __shfl_xor(m[r], 8));
    }
    float l[4] = {0.f, 0.f, 0.f, 0.f};
    #pragma unroll
    for (int j = 0; j < 13; ++j)
      #pragma unroll
      for (int r = 0; r < 4; ++r) {
        float e = __expf(acc[j][r] - m[r]);
        acc[j][r] = e; l[r] += e;
      }
    #pragma unroll
    for (int r = 0; r < 4; ++r) {
      l[r] += __shfl_xor(l[r], 1);
      l[r] += __shfl_xor(l[r], 2);
      l[r] += __shfl_xor(l[r], 4);
      l[r] += __shfl_xor(l[r], 8);
      l[r] = 1.f / l[r];
    }
    #pragma unroll
    for (int j = 0; j < 13; ++j)
      #pragma unroll
      for (int r = 0; r < 4; ++r) {
        const int g = ii * 16 + quad * 4 + r;
        attnP[((size_t)bh * GP_ + g) * SP_ + j * 16 + c] = f2bf(acc[j][r] * l[r]);
      }
  }
}

// ---------------- ctx = P @ V via MFMA, V^T staged in LDS ------------------
// grid (NH, B), block 256. P A-frags direct from global.
__global__ __launch_bounds__(256) void k_pv(const ushort* __restrict__ attnP,
    const ushort* __restrict__ VbT, ushort* __restrict__ ctx) {
  __shared__ ushort Vs[HD_ * SP_];   // 43008 B
  const int h = blockIdx.x, b = blockIdx.y, t = threadIdx.x;
  const int bh = b * NH_ + h;
  const int lane = t & 63, wave = t >> 6;
  const int quad = lane >> 4, c = lane & 15;
  const ushort* vsrc = VbT + (size_t)bh * HD_ * SP_;
  for (int i = t; i < HD_ * SP_ / 8; i += 256)   // 2688 chunks
    gl2lds16(vsrc + (size_t)i * 8, &Vs[i * 8]);
  __syncthreads();
  for (int ii = wave; ii < 7; ii += 4) {
    bf16x8 af[7];
    #pragma unroll
    for (int k = 0; k < 7; ++k)
      af[k] = *(const bf16x8*)(attnP + ((size_t)bh * GP_ + ii * 16 + c) * SP_ + k * 32 + quad * 8);
    #pragma unroll
    for (int j = 0; j < 6; ++j) {
      f32x4 acc = {};
      #pragma unroll
      for (int k = 0; k < 7; ++k) {
        bf16x8 bf = *(const bf16x8*)&Vs[(j * 16 + c) * SP_ + k * 32 + quad * 8];
        acc = __builtin_amdgcn_mfma_f32_16x16x32_bf16(af[k], bf, acc, 0, 0, 0);
      }
      #pragma unroll
      for (int r = 0; r < 4; ++r) {
        const int g = ii * 16 + quad * 4 + r;
        if (g < G_)
          ctx[((size_t)(b * G_ + g)) * D_ + h * HD_ + j * 16 + c] = f2bf(acc[r]);
      }
    }
  }
}

// ---------------- residual + LayerNorm -------------------------------------
__global__ __launch_bounds__(256) void k_lnres(const float* __restrict__ resid, int resid_mod,
    const float* __restrict__ add, const float* __restrict__ gamma, const float* __restrict__ beta,
    float* __restrict__ outf, ushort* __restrict__ outb) {
  const int row = blockIdx.x, t = threadIdx.x;
  __shared__ float r1[256], r2[256];
  const float* rrow = resid + (size_t)(resid_mod ? (row % G_) : row) * D_;
  const float* arow = add + (size_t)row * D_;
  float y[3]; float s = 0.f, sq = 0.f;
  #pragma unroll
  for (int i = 0; i < 3; ++i) {
    int d = t + i * 256;
    float v = rrow[d] + arow[d];
    y[i] = v; s += v; sq += v * v;
  }
  r1[t] = s; r2[t] = sq; __syncthreads();
  for (int o = 128; o > 0; o >>= 1) { if (t < o) { r1[t] += r1[t + o]; r2[t] += r2[t + o]; } __syncthreads(); }
  const float mean = r1[0] * (1.f / D_);
  const float var  = r2[0] * (1.f / D_) - mean * mean;
  const float w = rsqrtf(var + 1e-5f);
  #pragma unroll
  for (int i = 0; i < 3; ++i) {
    int d = t + i * 256;
    float v = (y[i] - mean) * w * gamma[d] + beta[d];
    if (outf) outf[(size_t)row * D_ + d] = v;
    if (outb) outb[(size_t)row * D_ + d] = f2bf(v);
  }
}

// ---------------- grouped head via MFMA ------------------------------------
__global__ __launch_bounds__(256) void k_head2(const ushort* __restrict__ h,
    const ushort* __restrict__ dupT, const float* __restrict__ dup_bias, float* __restrict__ out) {
  __shared__ ushort As[64 * 32];    // 4 KB
  __shared__ ushort Bs[FP_ * 32];   // 7 KB
  const int g = blockIdx.x, t = threadIdx.x;
  const int lane = t & 63, wave = t >> 6;
  const int quad = lane >> 4, lrow = lane & 15;
  const int srow = t >> 2, scol = (t & 3) * 8;
  f32x4 acc[7] = {};
  for (int k0 = 0; k0 < D_; k0 += 32) {
    gl2lds16(h + ((size_t)srow * G_ + g) * D_ + k0 + scol, &As[srow * 32 + scol]);
    for (int i = t; i < FP_ * 4; i += 256) {
      const int row = i >> 2, col = (i & 3) * 8;
      gl2lds16(dupT + ((size_t)g * FP_ + row) * D_ + k0 + col, &Bs[row * 32 + col]);
    }
    __syncthreads();
    bf16x8 af = *(const bf16x8*)&As[(wave * 16 + lrow) * 32 + quad * 8];
    #pragma unroll
    for (int j = 0; j < 7; ++j) {
      bf16x8 bfr = *(const bf16x8*)&Bs[(j * 16 + lrow) * 32 + quad * 8];
      acc[j] = __builtin_amdgcn_mfma_f32_16x16x32_bf16(af, bfr, acc[j], 0, 0, 0);
    }
    __syncthreads();
  }
  #pragma unroll
  for (int j = 0; j < 7; ++j) {
    const int f = j * 16 + lrow;
    if (f >= DF_) continue;
    const int n = g * DF_ + f;
    if (n >= NC_) continue;
    const float bv = dup_bias[n];
    #pragma unroll
    for (int r = 0; r < 4; ++r) {
      const int b = wave * 16 + quad * 4 + r;
      out[(size_t)b * NC_ + n] = acc[j][r] + bv;
    }
  }
}

// ---------------------------------------------------------------------------
// workspace layout (bytes)
// region 0 (0..51.4 MB): aemb (embed A), then attnP+VbT (attention), then ffB/ffoF (FFN)
// ---------------------------------------------------------------------------
static constexpr size_t OFF_AEMB  = 0;          // bf16 [12544,2048] = 51,380,224
static constexpr size_t OFF_ATTNP = 0;          // bf16 [512,112,224] = 25,690,112
static constexpr size_t OFF_VBT   = 25690112;   // bf16 [512,96,224]  = 22,020,096 (end 47,710,208)
static constexpr size_t OFF_FF    = 0;          // bf16 [6400,2048] = 26,214,400
static constexpr size_t OFF_FFO   = 26214400;   // f32  [6400,768]  = 19,660,800 (end 45,875,200)
static constexpr size_t OFF_WEMB  = 51380224;   // bf16 3,145,728
static constexpr size_t OFF_MEM   = 54525952;   // bf16 [12544,768] = 19,267,584
static constexpr size_t OFF_WK    = 73793536;   // 1,179,648
static constexpr size_t OFF_WV    = 74973184;   // 1,179,648
static constexpr size_t OFF_WO    = 76152832;   // 1,179,648
static constexpr size_t OFF_W1    = 77332480;   // 3,145,728
static constexpr size_t OFF_W2    = 80478208;   // 3,145,728
static constexpr size_t OFF_DUP   = 83623936;   // bf16 [100,112,768] = 17,203,200
static constexpr size_t OFF_KB    = 100827136;  // 19,267,584
static constexpr size_t OFF_VB    = 120094720;  // 19,267,584
static constexpr size_t OFF_TGT   = 139362304;  // 307,200
static constexpr size_t OFF_Q     = 139669504;  // bf16 [112,768] = 172,032
static constexpr size_t OFF_CTX   = 139976704;  // 9,830,400
static constexpr size_t OFF_CTXO  = 149807104;  // 19,660,800
static constexpr size_t OFF_TGT2F = 169467904;  // 19,660,800
static constexpr size_t OFF_TGT2B = 189128704;  // 9,830,400
static constexpr size_t OFF_HB    = 198959104;  // 9,830,400  (end 208,789,504)

extern "C" void kernel_launch(void* const* d_in, const int* in_sizes, int n_in,
                              void* d_out, int out_size, void* d_ws, size_t ws_size,
                              hipStream_t stream) {
  const float* x           = (const float*)d_in[0];
  const float* w_embed     = (const float*)d_in[1];
  const float* b_embed     = (const float*)d_in[2];
  const float* query_embed = (const float*)d_in[3];
  const float* wq          = (const float*)d_in[4];
  const float* bq          = (const float*)d_in[5];
  const float* wk          = (const float*)d_in[6];
  const float* bk          = (const float*)d_in[7];
  const float* wv          = (const float*)d_in[8];
  const float* bv          = (const float*)d_in[9];
  const float* wo          = (const float*)d_in[10];
  const float* bo          = (const float*)d_in[11];
  const float* g1          = (const float*)d_in[12];
  const float* be1         = (const float*)d_in[13];
  const float* g2          = (const float*)d_in[14];
  const float* be2         = (const float*)d_in[15];
  const float* g3          = (const float*)d_in[16];
  const float* be3         = (const float*)d_in[17];
  const float* w1          = (const float*)d_in[18];
  const float* bl1         = (const float*)d_in[19];
  const float* w2          = (const float*)d_in[20];
  const float* bl2         = (const float*)d_in[21];
  const float* dup_pool    = (const float*)d_in[22];
  const float* dup_bias    = (const float*)d_in[23];
  float* out = (float*)d_out;
  char* ws = (char*)d_ws;

  ushort* aemb  = (ushort*)(ws + OFF_AEMB);
  ushort* wembB = (ushort*)(ws + OFF_WEMB);
  ushort* memB  = (ushort*)(ws + OFF_MEM);
  ushort* wkB   = (ushort*)(ws + OFF_WK);
  ushort* wvB   = (ushort*)(ws + OFF_WV);
  ushort* woB   = (ushort*)(ws + OFF_WO);
  ushort* w1B   = (ushort*)(ws + OFF_W1);
  ushort* w2B   = (ushort*)(ws + OFF_W2);
  ushort* dupT  = (ushort*)(ws + OFF_DUP);
  ushort* Kb    = (ushort*)(ws + OFF_KB);
  ushort* Vb    = (ushort*)(ws + OFF_VB);
  float*  tgtF  = (float*)(ws + OFF_TGT);
  ushort* qB    = (ushort*)(ws + OFF_Q);
  ushort* attnP = (ushort*)(ws + OFF_ATTNP);
  ushort* VbT   = (ushort*)(ws + OFF_VBT);
  ushort* ctxB  = (ushort*)(ws + OFF_CTX);
  float*  ctxoF = (float*)(ws + OFF_CTXO);
  float*  tgt2F = (float*)(ws + OFF_TGT2F);
  ushort* tgt2B = (ushort*)(ws + OFF_TGT2B);
  ushort* ffB   = (ushort*)(ws + OFF_FF);
  float*  ffoF  = (float*)(ws + OFF_FFO);
  ushort* hB    = (ushort*)(ws + OFF_HB);

  // 1. weight conversions to bf16 (+ dup transpose)
  k_cvt4<<<1024, 256, 0, stream>>>(w_embed,  wembB, D_ * CIN_ / 4);
  k_cvt4<<<1024, 256, 0, stream>>>(wk,       wkB,   D_ * D_ / 4);
  k_cvt4<<<1024, 256, 0, stream>>>(wv,       wvB,   D_ * D_ / 4);
  k_cvt4<<<1024, 256, 0, stream>>>(wo,       woB,   D_ * D_ / 4);
  k_cvt4<<<1024, 256, 0, stream>>>(w1,       w1B,   FF_ * D_ / 4);
  k_cvt4<<<1024, 256, 0, stream>>>(w2,       w2B,   D_ * FF_ / 4);
  k_dupT<<<dim3(4, 24, G_), 256, 0, stream>>>(dup_pool, dupT);

  // 2. x transpose+convert -> A_emb [B*S, C]
  k_xpose<<<dim3(CIN_ / 32, 7, B_), 256, 0, stream>>>(x, aemb);

  // 3-4. tgt = LN(2*query_embed), qB = bf16(tgt@wq^T + bq) (batch-independent)
  k_tgt<<<G_, 256, 0, stream>>>(query_embed, g1, be1, tgtF);
  k_qproj<<<GP_, 256, 0, stream>>>(tgtF, wq, bq, qB);

  // 5. embed GEMM + relu -> mem bf16 [12544, 768]
  k_gemm<<<dim3(D_ / 128, BS_ / 128), 256, 0, stream>>>(aemb, wembB, b_embed, nullptr, memB,
                                                        BS_, D_, CIN_, 1);
  // 6-7. K/V projections -> bf16 [12544, 768]
  k_gemm<<<dim3(D_ / 128, BS_ / 128), 256, 0, stream>>>(memB, wkB, bk, nullptr, Kb, BS_, D_, D_, 0);
  k_gemm<<<dim3(D_ / 128, BS_ / 128), 256, 0, stream>>>(memB, wvB, bv, nullptr, Vb, BS_, D_, D_, 0);

  // 8. V transpose for PV B-operand
  k_vT<<<dim3(7, 3, B_ * NH_), 256, 0, stream>>>(Vb, VbT);

  // 9-10. MFMA attention
  k_scores<<<dim3(NH_, B_), 256, 0, stream>>>(qB, Kb, attnP);
  k_pv<<<dim3(NH_, B_), 256, 0, stream>>>(attnP, VbT, ctxB);

  // 11. ctx @ wo^T + bo -> fp32 [6400, 768]
  k_gemm<<<dim3(D_ / 128, BG_ / 128), 256, 0, stream>>>(ctxB, woB, bo, ctxoF, nullptr, BG_, D_, D_, 0);

  // 12. tgt2 = LN(tgt + ctxo)
  k_lnres<<<BG_, 256, 0, stream>>>(tgtF, 1, ctxoF, g2, be2, tgt2F, tgt2B);

  // 13-14. FFN
  k_gemm<<<dim3(FF_ / 128, BG_ / 128), 256, 0, stream>>>(tgt2B, w1B, bl1, nullptr, ffB, BG_, FF_, D_, 1);
  k_gemm<<<dim3(D_ / 128, BG_ / 128), 256, 0, stream>>>(ffB, w2B, bl2, ffoF, nullptr, BG_, D_, FF_, 0);

  // 15. h = LN(tgt2 + ffo) -> bf16
  k_lnres<<<BG_, 256, 0, stream>>>(tgt2F, 0, ffoF, g3, be3, nullptr, hB);

  // 16. grouped head -> logits fp32 [64, 9605] via MFMA
  k_head2<<<G_, 256, 0, stream>>>(hB, dupT, dup_bias, out);
}